// Round 18
// baseline (353.716 us; speedup 1.0000x reference)
//
#include <hip/hip_runtime.h>
#include <stdint.h>

#define D_MODEL 1024
#define HIDDEN  4096
#define SEQ     2048
#define NTOK    8192
#define NHEAD   16
#define HDIM    64

typedef unsigned short u16;
typedef __attribute__((ext_vector_type(8))) __bf16 bf16x8;
typedef __attribute__((ext_vector_type(4))) float f32x4;

__device__ __forceinline__ u16 f2bf(float f) {
  union { float f; unsigned u; } c; c.f = f;
  unsigned u = c.u + 0x7fffu + ((c.u >> 16) & 1u);
  return (u16)(u >> 16);
}

__device__ __forceinline__ float bf2f(u16 u) {
  union { unsigned u; float f; } c; c.u = (unsigned)u << 16;
  return c.f;
}

__device__ __forceinline__ void gload16(const void* g, void* l) {
  __builtin_amdgcn_global_load_lds((const __attribute__((address_space(1))) void*)g,
                                   (__attribute__((address_space(3))) void*)l, 16, 0, 0);
}

// ---------------- weight convert+transpose: 4x [1024][1024] f32 -> [1024][1024] bf16^T ----
__global__ void transpose_cvt4(const float* __restrict__ A0, const float* __restrict__ A1,
                               const float* __restrict__ A2, const float* __restrict__ A3,
                               u16* __restrict__ O) {
  __shared__ float t[32][33];
  const int z = blockIdx.z;
  const float* W = (z == 0) ? A0 : (z == 1) ? A1 : (z == 2) ? A2 : A3;
  u16* Wt = O + ((size_t)z << 20);
  const int k0 = blockIdx.y * 32, n0 = blockIdx.x * 32;
  const int tx = threadIdx.x, ty = threadIdx.y;  // 32 x 8
#pragma unroll
  for (int p = 0; p < 4; ++p)
    t[ty + p * 8][tx] = W[(size_t)(k0 + ty + p * 8) * D_MODEL + n0 + tx];
  __syncthreads();
#pragma unroll
  for (int p = 0; p < 4; ++p) {
    const int n = ty + p * 8;
    Wt[(size_t)(n0 + n) * D_MODEL + k0 + tx] = f2bf(t[tx][n]);
  }
}

// ---------------- weight convert + transpose: W[K][N] f32 -> Wt[N][K] bf16 ----------------
__global__ void transpose_cvt(const float* __restrict__ W, u16* __restrict__ Wt, int K, int N) {
  __shared__ float t[32][33];
  const int k0 = blockIdx.y * 32, n0 = blockIdx.x * 32;
  const int tx = threadIdx.x, ty = threadIdx.y;  // 32 x 8
#pragma unroll
  for (int p = 0; p < 4; ++p)
    t[ty + p * 8][tx] = W[(size_t)(k0 + ty + p * 8) * N + n0 + tx];
  __syncthreads();
#pragma unroll
  for (int p = 0; p < 4; ++p) {
    const int n = ty + p * 8;
    Wt[(size_t)(n0 + n) * K + k0 + tx] = f2bf(t[tx][n]);
  }
}

// ---------------- LayerNorm (f32 in): x f32 [NTOK][D] -> xn bf16 ----------------
__global__ __launch_bounds__(256)
void ln_kernel(const float* __restrict__ x, const float* __restrict__ gamma,
               const float* __restrict__ beta, u16* __restrict__ out) {
  const int row = blockIdx.x;
  const int tid = threadIdx.x;
  const float4 v = ((const float4*)(x + (size_t)row * D_MODEL))[tid];
  float s = v.x + v.y + v.z + v.w;
  float q = v.x * v.x + v.y * v.y + v.z * v.z + v.w * v.w;
#pragma unroll
  for (int o = 32; o > 0; o >>= 1) { s += __shfl_down(s, o); q += __shfl_down(q, o); }
  __shared__ float ps[4], pq[4];
  const int wid = tid >> 6, lane = tid & 63;
  if (lane == 0) { ps[wid] = s; pq[wid] = q; }
  __syncthreads();
  s = ps[0] + ps[1] + ps[2] + ps[3];
  q = pq[0] + pq[1] + pq[2] + pq[3];
  const float mean = s * (1.0f / D_MODEL);
  const float var = q * (1.0f / D_MODEL) - mean * mean;
  const float rstd = rsqrtf(var + 1e-10f);
  const float4 gv = ((const float4*)gamma)[tid];
  const float4 bv = ((const float4*)beta)[tid];
  ushort4 o4;
  o4.x = f2bf((v.x - mean) * rstd * gv.x + bv.x);
  o4.y = f2bf((v.y - mean) * rstd * gv.y + bv.y);
  o4.z = f2bf((v.z - mean) * rstd * gv.z + bv.z);
  o4.w = f2bf((v.w - mean) * rstd * gv.w + bv.w);
  ((ushort4*)(out + (size_t)row * D_MODEL))[tid] = o4;
}

// ---------------- LayerNorm (bf16 in): x1b bf16 [NTOK][D] -> xn bf16 ----------------
__global__ __launch_bounds__(256)
void ln_kernel_b(const u16* __restrict__ x, const float* __restrict__ gamma,
                 const float* __restrict__ beta, u16* __restrict__ out) {
  const int row = blockIdx.x;
  const int tid = threadIdx.x;
  const ushort4 uv = ((const ushort4*)(x + (size_t)row * D_MODEL))[tid];
  const float v0 = bf2f(uv.x), v1 = bf2f(uv.y), v2 = bf2f(uv.z), v3 = bf2f(uv.w);
  float s = v0 + v1 + v2 + v3;
  float q = v0 * v0 + v1 * v1 + v2 * v2 + v3 * v3;
#pragma unroll
  for (int o = 32; o > 0; o >>= 1) { s += __shfl_down(s, o); q += __shfl_down(q, o); }
  __shared__ float ps[4], pq[4];
  const int wid = tid >> 6, lane = tid & 63;
  if (lane == 0) { ps[wid] = s; pq[wid] = q; }
  __syncthreads();
  s = ps[0] + ps[1] + ps[2] + ps[3];
  q = pq[0] + pq[1] + pq[2] + pq[3];
  const float mean = s * (1.0f / D_MODEL);
  const float var = q * (1.0f / D_MODEL) - mean * mean;
  const float rstd = rsqrtf(var + 1e-10f);
  const float4 gv = ((const float4*)gamma)[tid];
  const float4 bv = ((const float4*)beta)[tid];
  ushort4 o4;
  o4.x = f2bf((v0 - mean) * rstd * gv.x + bv.x);
  o4.y = f2bf((v1 - mean) * rstd * gv.y + bv.y);
  o4.z = f2bf((v2 - mean) * rstd * gv.z + bv.z);
  o4.w = f2bf((v3 - mean) * rstd * gv.w + bv.w);
  ((ushort4*)(out + (size_t)row * D_MODEL))[tid] = o4;
}

// ---------------- gemm64: m97 structure, 128x128 tile, BK=64, 4 blocks/CU ----------------
// EPI 0: bf16 out, col bias.     EPI 1: f32 out += f32 res, col bias.
// EPI 2: gelu(erf)->bf16.  EPI 3: bf16, ROW bias, kv-permuted cols (V^T).
// EPI 6: fused QK dual output.  EPI 7: bf16 out = acc + bias + f32 res.
// EPI 8: f32 out = acc + bias + bf16 res.
template <int EPI, int KPY, int KPX>
__global__ __launch_bounds__(256, 4)
void gemm64(const u16* __restrict__ A, const u16* __restrict__ Bt,
            const float* __restrict__ bias, const float* __restrict__ bias2,
            const float* __restrict__ res, void* __restrict__ outp, void* __restrict__ outp2,
            int M, int N, int K) {
  __shared__ u16 As[128 * 64];
  __shared__ u16 Bs[128 * 64];
  const int tid = threadIdx.x;
  const int wid = tid >> 6, lane = tid & 63;
  const int g = lane >> 4, lr = lane & 15;
  const int wm = (wid & 1) << 6, wn = (wid >> 1) << 6;

  const int xcd = blockIdx.x & 7, l = blockIdx.x >> 3;
  int bx, by;
  if (KPY > 0) { by = xcd * KPY + (l % KPY); bx = l / KPY; }
  else         { bx = xcd * KPX + (l % KPX); by = l / KPX; }
  const int m0 = by * 128, n0 = bx * 128;

  const int NT = K >> 6;

  const int r0 = tid >> 3;
  const int csw = ((tid & 7) ^ (r0 & 7)) << 3;  // pre-swizzled u16 offset within row
  const u16* pA[4];
  const u16* pB[4];
#pragma unroll
  for (int i = 0; i < 4; ++i) {
    pA[i] = A + (size_t)(m0 + r0 + i * 32) * K + csw;
    pB[i] = Bt + (size_t)(n0 + r0 + i * 32) * K + csw;
  }
  const int db = (tid & 192) * 16;  // wave-uniform dest base (bytes)

  f32x4 acc[4][4] = {};

  for (int t = 0; t < NT; ++t) {
    __syncthreads();
#pragma unroll
    for (int i = 0; i < 4; ++i) {
      gload16(pA[i], (char*)As + db + i * 4096);
      gload16(pB[i], (char*)Bs + db + i * 4096);
      pA[i] += 64; pB[i] += 64;
    }
    __syncthreads();

#pragma unroll
    for (int ks = 0; ks < 2; ++ks) {
      bf16x8 af[4], bfr[4];
#pragma unroll
      for (int f = 0; f < 4; ++f) {
        const int ra = wm + f * 16 + lr;
        const int rb = wn + f * 16 + lr;
        const int co = ((ks * 4 + g) ^ (lr & 7)) * 8;
        af[f] = *(const bf16x8*)(As + ra * 64 + co);
        bfr[f] = *(const bf16x8*)(Bs + rb * 64 + co);
      }
      __builtin_amdgcn_s_setprio(1);
#pragma unroll
      for (int mf = 0; mf < 4; ++mf)
#pragma unroll
        for (int nf = 0; nf < 4; ++nf)
          acc[mf][nf] =
              __builtin_amdgcn_mfma_f32_16x16x32_bf16(af[mf], bfr[nf], acc[mf][nf], 0, 0, 0);
      __builtin_amdgcn_s_setprio(0);
    }
  }

  // ---- epilogue ----
#pragma unroll
  for (int mf = 0; mf < 4; ++mf)
#pragma unroll
    for (int nf = 0; nf < 4; ++nf) {
      const int gn = n0 + wn + nf * 16 + lr;
      const int gm = m0 + wm + mf * 16 + 4 * g;
#pragma unroll
      for (int r = 0; r < 4; ++r) {
        const float av = acc[mf][nf][r];
        if (EPI == 0) {
          ((u16*)outp)[(size_t)(gm + r) * N + gn] = f2bf(av + bias[gn]);
        } else if (EPI == 1) {
          const size_t idx = (size_t)(gm + r) * N + gn;
          ((float*)outp)[idx] = av + bias[gn] + res[idx];
        } else if (EPI == 2) {
          const float v = av + bias[gn];
          ((u16*)outp)[(size_t)(gm + r) * N + gn] =
              f2bf(0.5f * v * (1.0f + erff(v * 0.7071067811865475f)));
        } else if (EPI == 3) {
          const int gn_p = (gn & ~63) | ((gn & 15) << 2) | ((gn >> 4) & 3);
          ((u16*)outp)[(size_t)(gm + r) * N + gn_p] = f2bf(av + bias[gm + r]);
        } else if (EPI == 6) {
          const int side = gn >> 10, col = gn & 1023;
          u16* o = (u16*)(side ? outp2 : outp);
          float t_ = av + (side ? bias2[col] : bias[col]);
          if (!side) t_ *= 0.18033688011112042f;
          o[(size_t)(gm + r) * 1024 + col] = f2bf(t_);
        } else if (EPI == 7) {
          const size_t idx = (size_t)(gm + r) * N + gn;
          ((u16*)outp)[idx] = f2bf(av + bias[gn] + res[idx]);
        } else {  // EPI 8: f32 out = acc + bias + bf16 residual
          const size_t idx = (size_t)(gm + r) * N + gn;
          ((float*)outp)[idx] = av + bias[gn] + bf2f(((const u16*)res)[idx]);
        }
      }
    }
}

// ---------------- flash attention v7: gload_lds + double-buffered K/V ----------------
// Q bf16 (pre-scaled by 0.125*log2e); K bf16; Vt bf16 [D][NTOK] kv-permuted; ctx bf16.
// No-max softmax in base 2.  XCD-affine bh mapping.
// K/V: unpadded [64][64] dbuf, gemm64 chunk-XOR swizzle (pre-swizzled global src +
// same XOR on ds_read_b128 — conflict-free). Tile t+1's gloads issue right after the
// per-tile barrier; next barrier's per-wave vmcnt drain retires them — load latency
// hides under the full compute phase. ONE barrier per tile. P: padded own-wave buffer.
__global__ __launch_bounds__(256, 3)
void attn_kernel(const u16* __restrict__ Q, const u16* __restrict__ K,
                 const u16* __restrict__ Vt, u16* __restrict__ ctxo) {
  const int L = blockIdx.x;
  const int q0 = ((L >> 3) & 15) * 128;
  const int bh = ((L >> 7) << 3) | (L & 7);
  const int b = bh >> 4, h = bh & 15;
  const int tid = threadIdx.x, wid = tid >> 6, lane = tid & 63;
  const int g = lane >> 4, lr = lane & 15;
  const size_t base = ((size_t)b * SEQ) * D_MODEL + h * HDIM;
  const size_t vbase = ((size_t)h * HDIM) * NTOK + (size_t)b * SEQ;

#define AST 76
  __shared__ u16 Kd[2][64 * 64];
  __shared__ u16 Vd[2][64 * 64];
  __shared__ u16 Ps[128 * AST];

  const int qw = wid * 32;

  // ---- staging setup: thread covers chunks tid and tid+256 of each 64x64 tile ----
  const int rA = tid >> 3;                        // rows 0..31 (and +32)
  const int cswz = ((tid & 7) ^ (rA & 7)) << 3;   // pre-swizzled source col (u16)
  const u16* pK0 = K + base + (size_t)rA * D_MODEL + cswz;
  const u16* pK1 = pK0 + (size_t)32 * D_MODEL;
  const u16* pV0 = Vt + vbase + (size_t)rA * NTOK + cswz;
  const u16* pV1 = pV0 + (size_t)32 * NTOK;
  const int db = (tid & 192) * 16;                // wave-uniform dest base (bytes)

  auto stageKV = [&](int bufi, int kv) {
    char* kb = (char*)Kd[bufi];
    char* vb = (char*)Vd[bufi];
    gload16(pK0 + (size_t)kv * D_MODEL, kb + db);
    gload16(pK1 + (size_t)kv * D_MODEL, kb + db + 4096);
    gload16(pV0 + kv, vb + db);
    gload16(pV1 + kv, vb + db + 4096);
  };

  stageKV(0, 0);  // tile 0 in flight (lands under Q staging)

  // ---- stage Q tile through Ps (coalesced), read fragments to registers ----
#pragma unroll
  for (int i = 0; i < 4; ++i) {
    const int ch = tid + 256 * i, row = ch >> 3, j = ch & 7;
    *(bf16x8*)(Ps + row * AST + j * 8) =
        *(const bf16x8*)(Q + base + (size_t)(q0 + row) * D_MODEL + j * 8);
  }
  __syncthreads();
  bf16x8 aq[2][2];
#pragma unroll
  for (int qf = 0; qf < 2; ++qf)
#pragma unroll
    for (int ks = 0; ks < 2; ++ks)
      aq[qf][ks] = *(const bf16x8*)(Ps + (qw + qf * 16 + lr) * AST + ks * 32 + g * 8);

  f32x4 o[2][4] = {};
  float lrun[2][4] = {};

  for (int t = 0; t < SEQ / 64; ++t) {
    __syncthreads();  // tile t resident (per-wave vmcnt drain); buf[(t+1)&1] free
    if (t + 1 < SEQ / 64) stageKV((t + 1) & 1, (t + 1) * 64);
    const u16* Ksb = Kd[t & 1];
    const u16* Vsb = Vd[t & 1];

    // ---- QK^T ----
    f32x4 s[2][4] = {};
    __builtin_amdgcn_s_setprio(1);
#pragma unroll
    for (int ks = 0; ks < 2; ++ks)
#pragma unroll
      for (int kf = 0; kf < 4; ++kf) {
        const bf16x8 bk =
            *(const bf16x8*)(Ksb + (kf * 16 + lr) * 64 + (((ks << 2) | g) ^ (lr & 7)) * 8);
#pragma unroll
        for (int qf = 0; qf < 2; ++qf)
          s[qf][kf] = __builtin_amdgcn_mfma_f32_16x16x32_bf16(aq[qf][ks], bk, s[qf][kf], 0, 0, 0);
      }
    __builtin_amdgcn_s_setprio(0);

    // ---- p = 2^s (base-2 softmax, Q pre-scaled), accumulate l, cvt_pk, write P ----
#pragma unroll
    for (int qf = 0; qf < 2; ++qf)
#pragma unroll
      for (int r = 0; r < 4; ++r) {
        float p0, p1, p2, p3;
        asm("v_exp_f32 %0, %1" : "=v"(p0) : "v"(s[qf][0][r]));
        asm("v_exp_f32 %0, %1" : "=v"(p1) : "v"(s[qf][1][r]));
        asm("v_exp_f32 %0, %1" : "=v"(p2) : "v"(s[qf][2][r]));
        asm("v_exp_f32 %0, %1" : "=v"(p3) : "v"(s[qf][3][r]));
        lrun[qf][r] += (p0 + p1) + (p2 + p3);
        unsigned lo, hi;
        asm("v_cvt_pk_bf16_f32 %0, %1, %2" : "=v"(lo) : "v"(p0), "v"(p1));
        asm("v_cvt_pk_bf16_f32 %0, %1, %2" : "=v"(hi) : "v"(p2), "v"(p3));
        *(uint2*)(Ps + (qw + qf * 16 + 4 * g + r) * AST + lr * 4) = make_uint2(lo, hi);
      }
    asm volatile("s_waitcnt lgkmcnt(0)" ::: "memory");  // own-wave P writes retired

    // ---- PV: o += P @ V ----
    __builtin_amdgcn_s_setprio(1);
#pragma unroll
    for (int ks = 0; ks < 2; ++ks) {
      bf16x8 pf[2];
#pragma unroll
      for (int qf = 0; qf < 2; ++qf)
        pf[qf] = *(const bf16x8*)(Ps + (qw + qf * 16 + lr) * AST + ks * 32 + g * 8);
#pragma unroll
      for (int df = 0; df < 4; ++df) {
        const bf16x8 vf =
            *(const bf16x8*)(Vsb + (df * 16 + lr) * 64 + (((ks << 2) | g) ^ (lr & 7)) * 8);
#pragma unroll
        for (int qf = 0; qf < 2; ++qf)
          o[qf][df] = __builtin_amdgcn_mfma_f32_16x16x32_bf16(pf[qf], vf, o[qf][df], 0, 0, 0);
      }
    }
    __builtin_amdgcn_s_setprio(0);
  }

  // ---- final l reduction across the 16 lanes sharing each row ----
#pragma unroll
  for (int off = 1; off < 16; off <<= 1)
#pragma unroll
    for (int qf = 0; qf < 2; ++qf)
#pragma unroll
      for (int r = 0; r < 4; ++r)
        lrun[qf][r] += __shfl_xor(lrun[qf][r], off);

  // ---- epilogue: ctx = o / l ----
#pragma unroll
  for (int qf = 0; qf < 2; ++qf)
#pragma unroll
    for (int r = 0; r < 4; ++r) {
      const float rinv = 1.0f / lrun[qf][r];
      const int qrow = q0 + qw + qf * 16 + 4 * g + r;
#pragma unroll
      for (int df = 0; df < 4; ++df)
        ctxo[base + (size_t)qrow * D_MODEL + df * 16 + lr] = f2bf(o[qf][df][r] * rinv);
    }
#undef AST
}

extern "C" void kernel_launch(void* const* d_in, const int* in_sizes, int n_in,
                              void* d_out, int out_size, void* d_ws, size_t ws_size,
                              hipStream_t stream) {
  const float* x  = (const float*)d_in[0];
  const float* Wq = (const float*)d_in[1];
  const float* bq = (const float*)d_in[2];
  const float* Wk = (const float*)d_in[3];
  const float* bk = (const float*)d_in[4];
  const float* Wv = (const float*)d_in[5];
  const float* bv = (const float*)d_in[6];
  const float* Wo = (const float*)d_in[7];
  const float* bo = (const float*)d_in[8];
  const float* W1 = (const float*)d_in[9];
  const float* b1 = (const float*)d_in[10];
  const float* W2 = (const float*)d_in[11];
  const float* b2 = (const float*)d_in[12];
  const float* gamma1 = (const float*)d_in[13];
  const float* beta1  = (const float*)d_in[14];
  const float* gamma2 = (const float*)d_in[15];
  const float* beta2  = (const float*)d_in[16];
  float* out = (float*)d_out;

  const size_t M1 = 1u << 20;  // 1M elems
  u16* w   = (u16*)d_ws;
  u16* WtQ = w;                // [1024][1024]; WtK adjacent -> fused Bt [2048][1024]
  u16* WtV = w + 2 * M1;
  u16* WtO = w + 3 * M1;
  u16* Wt1 = w + 4 * M1;   // [4096][1024]
  u16* Wt2 = w + 8 * M1;   // [1024][4096]
  u16* xn  = w + 12 * M1;
  u16* Qb  = w + 20 * M1;
  u16* Kb  = w + 28 * M1;
  u16* Vtb = w + 36 * M1;  // V^T [1024][8192], kv-permuted within 64-blocks
  u16* ctx = w + 44 * M1;
  u16* hb  = w + 20 * M1;  // h [8192][4096] aliases Q/K/Vt/ctx (dead by FFN1)
  u16* x1b = w + 52 * M1;  // x1 residual in bf16 [8192][1024]

  const dim3 tb(32, 8);
  transpose_cvt4<<<dim3(32, 32, 4), tb, 0, stream>>>(Wq, Wk, Wv, Wo, WtQ);
  transpose_cvt<<<dim3(HIDDEN / 32, D_MODEL / 32), tb, 0, stream>>>(W1, Wt1, D_MODEL, HIDDEN);
  transpose_cvt<<<dim3(D_MODEL / 32, HIDDEN / 32), tb, 0, stream>>>(W2, Wt2, HIDDEN, D_MODEL);

  ln_kernel<<<NTOK, 256, 0, stream>>>(x, gamma1, beta1, xn);

  // fused Q+K projection: Bt = [WtQ;WtK], N=2048 -> 1024 blocks
  gemm64<6, 8, 0><<<1024, 256, 0, stream>>>(xn, WtQ, bq, bk, nullptr, Qb, Kb,
                                            NTOK, 2048, D_MODEL);
  // V^T: C[d][s] = WtV[d][:] . xn[s][:]  (row bias bv[d]), kv-permuted columns
  gemm64<3, 0, 8><<<512, 256, 0, stream>>>(WtV, xn, bv, nullptr, nullptr, Vtb, nullptr,
                                           D_MODEL, NTOK, D_MODEL);

  attn_kernel<<<1024, 256, 0, stream>>>(Qb, Kb, Vtb, ctx);

  // Wo + residual(x f32) -> x1b (bf16)
  gemm64<7, 8, 0><<<512, 256, 0, stream>>>(ctx, WtO, bo, nullptr, x, x1b, nullptr,
                                           NTOK, D_MODEL, D_MODEL);

  ln_kernel_b<<<NTOK, 256, 0, stream>>>(x1b, gamma2, beta2, xn);

  // FFN1: gemm64, full chip
  gemm64<2, 8, 0><<<2048, 256, 0, stream>>>(xn, Wt1, b1, nullptr, nullptr, hb, nullptr,
                                            NTOK, HIDDEN, D_MODEL);
  // FFN2 + residual(x1b bf16) -> out (f32)
  gemm64<8, 8, 0><<<512, 256, 0, stream>>>(hb, Wt2, b2, nullptr, (const float*)x1b, out,
                                           nullptr, NTOK, D_MODEL, HIDDEN);
}

// Round 19
// 346.689 us; speedup vs baseline: 1.0203x; 1.0203x over previous
//
#include <hip/hip_runtime.h>
#include <stdint.h>

#define D_MODEL 1024
#define HIDDEN  4096
#define SEQ     2048
#define NTOK    8192
#define NHEAD   16
#define HDIM    64

typedef unsigned short u16;
typedef __attribute__((ext_vector_type(8))) __bf16 bf16x8;
typedef __attribute__((ext_vector_type(4))) float f32x4;

__device__ __forceinline__ u16 f2bf(float f) {
  union { float f; unsigned u; } c; c.f = f;
  unsigned u = c.u + 0x7fffu + ((c.u >> 16) & 1u);
  return (u16)(u >> 16);
}

__device__ __forceinline__ float bf2f(u16 u) {
  union { unsigned u; float f; } c; c.u = (unsigned)u << 16;
  return c.f;
}

__device__ __forceinline__ void gload16(const void* g, void* l) {
  __builtin_amdgcn_global_load_lds((const __attribute__((address_space(1))) void*)g,
                                   (__attribute__((address_space(3))) void*)l, 16, 0, 0);
}

// ---------------- weight convert+transpose: 4x [1024][1024] f32 -> [1024][1024] bf16^T ----
__global__ void transpose_cvt4(const float* __restrict__ A0, const float* __restrict__ A1,
                               const float* __restrict__ A2, const float* __restrict__ A3,
                               u16* __restrict__ O) {
  __shared__ float t[32][33];
  const int z = blockIdx.z;
  const float* W = (z == 0) ? A0 : (z == 1) ? A1 : (z == 2) ? A2 : A3;
  u16* Wt = O + ((size_t)z << 20);
  const int k0 = blockIdx.y * 32, n0 = blockIdx.x * 32;
  const int tx = threadIdx.x, ty = threadIdx.y;  // 32 x 8
#pragma unroll
  for (int p = 0; p < 4; ++p)
    t[ty + p * 8][tx] = W[(size_t)(k0 + ty + p * 8) * D_MODEL + n0 + tx];
  __syncthreads();
#pragma unroll
  for (int p = 0; p < 4; ++p) {
    const int n = ty + p * 8;
    Wt[(size_t)(n0 + n) * D_MODEL + k0 + tx] = f2bf(t[tx][n]);
  }
}

// ---------------- weight convert + transpose: W[K][N] f32 -> Wt[N][K] bf16 ----------------
__global__ void transpose_cvt(const float* __restrict__ W, u16* __restrict__ Wt, int K, int N) {
  __shared__ float t[32][33];
  const int k0 = blockIdx.y * 32, n0 = blockIdx.x * 32;
  const int tx = threadIdx.x, ty = threadIdx.y;  // 32 x 8
#pragma unroll
  for (int p = 0; p < 4; ++p)
    t[ty + p * 8][tx] = W[(size_t)(k0 + ty + p * 8) * N + n0 + tx];
  __syncthreads();
#pragma unroll
  for (int p = 0; p < 4; ++p) {
    const int n = ty + p * 8;
    Wt[(size_t)(n0 + n) * K + k0 + tx] = f2bf(t[tx][n]);
  }
}

// ---------------- LayerNorm (f32 in): x f32 [NTOK][D] -> xn bf16 ----------------
__global__ __launch_bounds__(256)
void ln_kernel(const float* __restrict__ x, const float* __restrict__ gamma,
               const float* __restrict__ beta, u16* __restrict__ out) {
  const int row = blockIdx.x;
  const int tid = threadIdx.x;
  const float4 v = ((const float4*)(x + (size_t)row * D_MODEL))[tid];
  float s = v.x + v.y + v.z + v.w;
  float q = v.x * v.x + v.y * v.y + v.z * v.z + v.w * v.w;
#pragma unroll
  for (int o = 32; o > 0; o >>= 1) { s += __shfl_down(s, o); q += __shfl_down(q, o); }
  __shared__ float ps[4], pq[4];
  const int wid = tid >> 6, lane = tid & 63;
  if (lane == 0) { ps[wid] = s; pq[wid] = q; }
  __syncthreads();
  s = ps[0] + ps[1] + ps[2] + ps[3];
  q = pq[0] + pq[1] + pq[2] + pq[3];
  const float mean = s * (1.0f / D_MODEL);
  const float var = q * (1.0f / D_MODEL) - mean * mean;
  const float rstd = rsqrtf(var + 1e-10f);
  const float4 gv = ((const float4*)gamma)[tid];
  const float4 bv = ((const float4*)beta)[tid];
  ushort4 o4;
  o4.x = f2bf((v.x - mean) * rstd * gv.x + bv.x);
  o4.y = f2bf((v.y - mean) * rstd * gv.y + bv.y);
  o4.z = f2bf((v.z - mean) * rstd * gv.z + bv.z);
  o4.w = f2bf((v.w - mean) * rstd * gv.w + bv.w);
  ((ushort4*)(out + (size_t)row * D_MODEL))[tid] = o4;
}

// ---------------- LayerNorm (bf16 in): x1b bf16 [NTOK][D] -> xn bf16 ----------------
__global__ __launch_bounds__(256)
void ln_kernel_b(const u16* __restrict__ x, const float* __restrict__ gamma,
                 const float* __restrict__ beta, u16* __restrict__ out) {
  const int row = blockIdx.x;
  const int tid = threadIdx.x;
  const ushort4 uv = ((const ushort4*)(x + (size_t)row * D_MODEL))[tid];
  const float v0 = bf2f(uv.x), v1 = bf2f(uv.y), v2 = bf2f(uv.z), v3 = bf2f(uv.w);
  float s = v0 + v1 + v2 + v3;
  float q = v0 * v0 + v1 * v1 + v2 * v2 + v3 * v3;
#pragma unroll
  for (int o = 32; o > 0; o >>= 1) { s += __shfl_down(s, o); q += __shfl_down(q, o); }
  __shared__ float ps[4], pq[4];
  const int wid = tid >> 6, lane = tid & 63;
  if (lane == 0) { ps[wid] = s; pq[wid] = q; }
  __syncthreads();
  s = ps[0] + ps[1] + ps[2] + ps[3];
  q = pq[0] + pq[1] + pq[2] + pq[3];
  const float mean = s * (1.0f / D_MODEL);
  const float var = q * (1.0f / D_MODEL) - mean * mean;
  const float rstd = rsqrtf(var + 1e-10f);
  const float4 gv = ((const float4*)gamma)[tid];
  const float4 bv = ((const float4*)beta)[tid];
  ushort4 o4;
  o4.x = f2bf((v0 - mean) * rstd * gv.x + bv.x);
  o4.y = f2bf((v1 - mean) * rstd * gv.y + bv.y);
  o4.z = f2bf((v2 - mean) * rstd * gv.z + bv.z);
  o4.w = f2bf((v3 - mean) * rstd * gv.w + bv.w);
  ((ushort4*)(out + (size_t)row * D_MODEL))[tid] = o4;
}

// ---------------- gemm64: m97 structure, 128x128 tile, BK=64, 4 blocks/CU ----------------
// 256 threads = 4 waves (2m x 2n), per-wave 64x64 (4x4 frags), 32 MFMA / iter.
// Single 32 KB LDS buffer, __syncthreads (compiler vmcnt drain), 8 gload16/thread.
// 8-chunk XOR swizzle (c ^ row&7): fragment ds_read_b128 fully conflict-free.
// EPI 0: bf16 out, col bias.     EPI 1: f32 out += f32 res, col bias.
// EPI 2: gelu(erf)->bf16.  EPI 3: bf16, ROW bias, kv-permuted cols (V^T).
// EPI 6: fused QK dual output.  EPI 7: bf16 out = acc + bias + f32 res.
// EPI 8: f32 out = acc + bias + bf16 res.
template <int EPI, int KPY, int KPX>
__global__ __launch_bounds__(256, 4)
void gemm64(const u16* __restrict__ A, const u16* __restrict__ Bt,
            const float* __restrict__ bias, const float* __restrict__ bias2,
            const float* __restrict__ res, void* __restrict__ outp, void* __restrict__ outp2,
            int M, int N, int K) {
  __shared__ u16 As[128 * 64];
  __shared__ u16 Bs[128 * 64];
  const int tid = threadIdx.x;
  const int wid = tid >> 6, lane = tid & 63;
  const int g = lane >> 4, lr = lane & 15;
  const int wm = (wid & 1) << 6, wn = (wid >> 1) << 6;

  const int xcd = blockIdx.x & 7, l = blockIdx.x >> 3;
  int bx, by;
  if (KPY > 0) { by = xcd * KPY + (l % KPY); bx = l / KPY; }
  else         { bx = xcd * KPX + (l % KPX); by = l / KPX; }
  const int m0 = by * 128, n0 = bx * 128;

  const int NT = K >> 6;

  const int r0 = tid >> 3;
  const int csw = ((tid & 7) ^ (r0 & 7)) << 3;  // pre-swizzled u16 offset within row
  const u16* pA[4];
  const u16* pB[4];
#pragma unroll
  for (int i = 0; i < 4; ++i) {
    pA[i] = A + (size_t)(m0 + r0 + i * 32) * K + csw;
    pB[i] = Bt + (size_t)(n0 + r0 + i * 32) * K + csw;
  }
  const int db = (tid & 192) * 16;  // wave-uniform dest base (bytes)

  f32x4 acc[4][4] = {};

  for (int t = 0; t < NT; ++t) {
    __syncthreads();
#pragma unroll
    for (int i = 0; i < 4; ++i) {
      gload16(pA[i], (char*)As + db + i * 4096);
      gload16(pB[i], (char*)Bs + db + i * 4096);
      pA[i] += 64; pB[i] += 64;
    }
    __syncthreads();

#pragma unroll
    for (int ks = 0; ks < 2; ++ks) {
      bf16x8 af[4], bfr[4];
#pragma unroll
      for (int f = 0; f < 4; ++f) {
        const int ra = wm + f * 16 + lr;
        const int rb = wn + f * 16 + lr;
        const int co = ((ks * 4 + g) ^ (lr & 7)) * 8;
        af[f] = *(const bf16x8*)(As + ra * 64 + co);
        bfr[f] = *(const bf16x8*)(Bs + rb * 64 + co);
      }
      __builtin_amdgcn_s_setprio(1);
#pragma unroll
      for (int mf = 0; mf < 4; ++mf)
#pragma unroll
        for (int nf = 0; nf < 4; ++nf)
          acc[mf][nf] =
              __builtin_amdgcn_mfma_f32_16x16x32_bf16(af[mf], bfr[nf], acc[mf][nf], 0, 0, 0);
      __builtin_amdgcn_s_setprio(0);
    }
  }

  // ---- epilogue ----
#pragma unroll
  for (int mf = 0; mf < 4; ++mf)
#pragma unroll
    for (int nf = 0; nf < 4; ++nf) {
      const int gn = n0 + wn + nf * 16 + lr;
      const int gm = m0 + wm + mf * 16 + 4 * g;
#pragma unroll
      for (int r = 0; r < 4; ++r) {
        const float av = acc[mf][nf][r];
        if (EPI == 0) {
          ((u16*)outp)[(size_t)(gm + r) * N + gn] = f2bf(av + bias[gn]);
        } else if (EPI == 1) {
          const size_t idx = (size_t)(gm + r) * N + gn;
          ((float*)outp)[idx] = av + bias[gn] + res[idx];
        } else if (EPI == 2) {
          const float v = av + bias[gn];
          ((u16*)outp)[(size_t)(gm + r) * N + gn] =
              f2bf(0.5f * v * (1.0f + erff(v * 0.7071067811865475f)));
        } else if (EPI == 3) {
          const int gn_p = (gn & ~63) | ((gn & 15) << 2) | ((gn >> 4) & 3);
          ((u16*)outp)[(size_t)(gm + r) * N + gn_p] = f2bf(av + bias[gm + r]);
        } else if (EPI == 6) {
          const int side = gn >> 10, col = gn & 1023;
          u16* o = (u16*)(side ? outp2 : outp);
          float t_ = av + (side ? bias2[col] : bias[col]);
          if (!side) t_ *= 0.18033688011112042f;
          o[(size_t)(gm + r) * 1024 + col] = f2bf(t_);
        } else if (EPI == 7) {
          const size_t idx = (size_t)(gm + r) * N + gn;
          ((u16*)outp)[idx] = f2bf(av + bias[gn] + res[idx]);
        } else {  // EPI 8: f32 out = acc + bias + bf16 residual
          const size_t idx = (size_t)(gm + r) * N + gn;
          ((float*)outp)[idx] = av + bias[gn] + bf2f(((const u16*)res)[idx]);
        }
      }
    }
}

// ---------------- flash attention v5 (round-11/13/17 proven, 91.7 us) ----------------
// Q bf16 (pre-scaled by 0.125*log2e); K bf16; Vt bf16 [D][NTOK] kv-permuted; ctx bf16.
// No-max softmax in base 2.  Stride 76 (2-way banks).  XCD-affine bh mapping.
__global__ __launch_bounds__(256, 4)
void attn_kernel(const u16* __restrict__ Q, const u16* __restrict__ K,
                 const u16* __restrict__ Vt, u16* __restrict__ ctxo) {
  const int L = blockIdx.x;
  const int q0 = ((L >> 3) & 15) * 128;
  const int bh = ((L >> 7) << 3) | (L & 7);
  const int b = bh >> 4, h = bh & 15;
  const int tid = threadIdx.x, wid = tid >> 6, lane = tid & 63;
  const int g = lane >> 4, lr = lane & 15;
  const size_t base = ((size_t)b * SEQ) * D_MODEL + h * HDIM;
  const size_t vbase = ((size_t)h * HDIM) * NTOK + (size_t)b * SEQ;

#define AST 76
  __shared__ u16 Ks[64 * AST];
  __shared__ u16 Vts[64 * AST];
  __shared__ u16 Ps[128 * AST];

  const int qw = wid * 32;

#pragma unroll
  for (int i = 0; i < 4; ++i) {
    const int ch = tid + 256 * i, row = ch >> 3, j = ch & 7;
    *(bf16x8*)(Ps + row * AST + j * 8) =
        *(const bf16x8*)(Q + base + (size_t)(q0 + row) * D_MODEL + j * 8);
  }
  __syncthreads();
  bf16x8 aq[2][2];
#pragma unroll
  for (int qf = 0; qf < 2; ++qf)
#pragma unroll
    for (int ks = 0; ks < 2; ++ks)
      aq[qf][ks] = *(const bf16x8*)(Ps + (qw + qf * 16 + lr) * AST + ks * 32 + g * 8);

  f32x4 o[2][4] = {};
  float lrun[2][4] = {};

  for (int kv0 = 0; kv0 < SEQ; kv0 += 64) {
    __syncthreads();
#pragma unroll
    for (int i = 0; i < 2; ++i) {
      const int row = (tid >> 3) + i * 32, j = tid & 7;
      *(bf16x8*)(Ks + row * AST + j * 8) =
          *(const bf16x8*)(K + base + (size_t)(kv0 + row) * D_MODEL + j * 8);
      *(bf16x8*)(Vts + row * AST + j * 8) =
          *(const bf16x8*)(Vt + vbase + (size_t)row * NTOK + kv0 + j * 8);
    }
    __syncthreads();

    f32x4 s[2][4] = {};
    __builtin_amdgcn_s_setprio(1);
#pragma unroll
    for (int ks = 0; ks < 2; ++ks)
#pragma unroll
      for (int kf = 0; kf < 4; ++kf) {
        const bf16x8 bk = *(const bf16x8*)(Ks + (kf * 16 + lr) * AST + ks * 32 + g * 8);
#pragma unroll
        for (int qf = 0; qf < 2; ++qf)
          s[qf][kf] = __builtin_amdgcn_mfma_f32_16x16x32_bf16(aq[qf][ks], bk, s[qf][kf], 0, 0, 0);
      }
    __builtin_amdgcn_s_setprio(0);

#pragma unroll
    for (int qf = 0; qf < 2; ++qf)
#pragma unroll
      for (int r = 0; r < 4; ++r) {
        float p0, p1, p2, p3;
        asm("v_exp_f32 %0, %1" : "=v"(p0) : "v"(s[qf][0][r]));
        asm("v_exp_f32 %0, %1" : "=v"(p1) : "v"(s[qf][1][r]));
        asm("v_exp_f32 %0, %1" : "=v"(p2) : "v"(s[qf][2][r]));
        asm("v_exp_f32 %0, %1" : "=v"(p3) : "v"(s[qf][3][r]));
        lrun[qf][r] += (p0 + p1) + (p2 + p3);
        unsigned lo, hi;
        asm("v_cvt_pk_bf16_f32 %0, %1, %2" : "=v"(lo) : "v"(p0), "v"(p1));
        asm("v_cvt_pk_bf16_f32 %0, %1, %2" : "=v"(hi) : "v"(p2), "v"(p3));
        *(uint2*)(Ps + (qw + qf * 16 + 4 * g + r) * AST + lr * 4) = make_uint2(lo, hi);
      }
    asm volatile("s_waitcnt lgkmcnt(0)" ::: "memory");

    __builtin_amdgcn_s_setprio(1);
#pragma unroll
    for (int ks = 0; ks < 2; ++ks) {
      bf16x8 pf[2];
#pragma unroll
      for (int qf = 0; qf < 2; ++qf)
        pf[qf] = *(const bf16x8*)(Ps + (qw + qf * 16 + lr) * AST + ks * 32 + g * 8);
#pragma unroll
      for (int df = 0; df < 4; ++df) {
        const bf16x8 vf = *(const bf16x8*)(Vts + (df * 16 + lr) * AST + ks * 32 + g * 8);
#pragma unroll
        for (int qf = 0; qf < 2; ++qf)
          o[qf][df] = __builtin_amdgcn_mfma_f32_16x16x32_bf16(pf[qf], vf, o[qf][df], 0, 0, 0);
      }
    }
    __builtin_amdgcn_s_setprio(0);
  }

#pragma unroll
  for (int off = 1; off < 16; off <<= 1)
#pragma unroll
    for (int qf = 0; qf < 2; ++qf)
#pragma unroll
      for (int r = 0; r < 4; ++r)
        lrun[qf][r] += __shfl_xor(lrun[qf][r], off);

#pragma unroll
  for (int qf = 0; qf < 2; ++qf)
#pragma unroll
    for (int r = 0; r < 4; ++r) {
      const float rinv = 1.0f / lrun[qf][r];
      const int qrow = q0 + qw + qf * 16 + 4 * g + r;
#pragma unroll
      for (int df = 0; df < 4; ++df)
        ctxo[base + (size_t)qrow * D_MODEL + df * 16 + lr] = f2bf(o[qf][df][r] * rinv);
    }
#undef AST
}

extern "C" void kernel_launch(void* const* d_in, const int* in_sizes, int n_in,
                              void* d_out, int out_size, void* d_ws, size_t ws_size,
                              hipStream_t stream) {
  const float* x  = (const float*)d_in[0];
  const float* Wq = (const float*)d_in[1];
  const float* bq = (const float*)d_in[2];
  const float* Wk = (const float*)d_in[3];
  const float* bk = (const float*)d_in[4];
  const float* Wv = (const float*)d_in[5];
  const float* bv = (const float*)d_in[6];
  const float* Wo = (const float*)d_in[7];
  const float* bo = (const float*)d_in[8];
  const float* W1 = (const float*)d_in[9];
  const float* b1 = (const float*)d_in[10];
  const float* W2 = (const float*)d_in[11];
  const float* b2 = (const float*)d_in[12];
  const float* gamma1 = (const float*)d_in[13];
  const float* beta1  = (const float*)d_in[14];
  const float* gamma2 = (const float*)d_in[15];
  const float* beta2  = (const float*)d_in[16];
  float* out = (float*)d_out;

  const size_t M1 = 1u << 20;  // 1M elems
  u16* w   = (u16*)d_ws;
  u16* WtQ = w;                // [1024][1024]; WtK adjacent -> fused Bt [2048][1024]
  u16* WtV = w + 2 * M1;
  u16* WtO = w + 3 * M1;
  u16* Wt1 = w + 4 * M1;   // [4096][1024]
  u16* Wt2 = w + 8 * M1;   // [1024][4096]
  u16* xn  = w + 12 * M1;
  u16* Qb  = w + 20 * M1;
  u16* Kb  = w + 28 * M1;
  u16* Vtb = w + 36 * M1;  // V^T [1024][8192], kv-permuted within 64-blocks
  u16* ctx = w + 44 * M1;
  u16* hb  = w + 20 * M1;  // h [8192][4096] aliases Q/K/Vt/ctx (dead by FFN1)
  u16* x1b = w + 52 * M1;  // x1 residual in bf16 [8192][1024]

  const dim3 tb(32, 8);
  transpose_cvt4<<<dim3(32, 32, 4), tb, 0, stream>>>(Wq, Wk, Wv, Wo, WtQ);
  transpose_cvt<<<dim3(HIDDEN / 32, D_MODEL / 32), tb, 0, stream>>>(W1, Wt1, D_MODEL, HIDDEN);
  transpose_cvt<<<dim3(D_MODEL / 32, HIDDEN / 32), tb, 0, stream>>>(W2, Wt2, HIDDEN, D_MODEL);

  ln_kernel<<<NTOK, 256, 0, stream>>>(x, gamma1, beta1, xn);

  // fused Q+K projection: Bt = [WtQ;WtK], N=2048 -> 1024 blocks
  gemm64<6, 8, 0><<<1024, 256, 0, stream>>>(xn, WtQ, bq, bk, nullptr, Qb, Kb,
                                            NTOK, 2048, D_MODEL);
  // V^T: C[d][s] = WtV[d][:] . xn[s][:]  (row bias bv[d]), kv-permuted columns
  gemm64<3, 0, 8><<<512, 256, 0, stream>>>(WtV, xn, bv, nullptr, nullptr, Vtb, nullptr,
                                           D_MODEL, NTOK, D_MODEL);

  attn_kernel<<<1024, 256, 0, stream>>>(Qb, Kb, Vtb, ctx);

  // Wo + residual(x f32) -> x1b (bf16)
  gemm64<7, 8, 0><<<512, 256, 0, stream>>>(ctx, WtO, bo, nullptr, x, x1b, nullptr,
                                           NTOK, D_MODEL, D_MODEL);

  ln_kernel_b<<<NTOK, 256, 0, stream>>>(x1b, gamma2, beta2, xn);

  // FFN1: gemm64, full chip
  gemm64<2, 8, 0><<<2048, 256, 0, stream>>>(xn, Wt1, b1, nullptr, nullptr, hb, nullptr,
                                            NTOK, HIDDEN, D_MODEL);
  // FFN2 + residual(x1b bf16) -> out (f32)
  gemm64<8, 8, 0><<<512, 256, 0, stream>>>(hb, Wt2, b2, nullptr, (const float*)x1b, out,
                                           nullptr, NTOK, D_MODEL, HIDDEN);
}

// Round 20
// 343.334 us; speedup vs baseline: 1.0302x; 1.0098x over previous
//
#include <hip/hip_runtime.h>
#include <stdint.h>

#define D_MODEL 1024
#define HIDDEN  4096
#define SEQ     2048
#define NTOK    8192
#define NHEAD   16
#define HDIM    64

typedef unsigned short u16;
typedef __attribute__((ext_vector_type(8))) __bf16 bf16x8;
typedef __attribute__((ext_vector_type(4))) float f32x4;

__device__ __forceinline__ u16 f2bf(float f) {
  union { float f; unsigned u; } c; c.f = f;
  unsigned u = c.u + 0x7fffu + ((c.u >> 16) & 1u);
  return (u16)(u >> 16);
}

__device__ __forceinline__ float bf2f(u16 u) {
  union { unsigned u; float f; } c; c.u = (unsigned)u << 16;
  return c.f;
}

__device__ __forceinline__ void gload16(const void* g, void* l) {
  __builtin_amdgcn_global_load_lds((const __attribute__((address_space(1))) void*)g,
                                   (__attribute__((address_space(3))) void*)l, 16, 0, 0);
}

// ---------------- fused prologue: 6 weight transposes + LN1, one launch ----------------
// blocks [0,4096):    4x square [1024][1024] f32 -> bf16^T   (z = id>>10)
// blocks [4096,8192):  W1 [1024][4096] -> Wt1 [4096][1024]
// blocks [8192,12288): W2 [4096][1024] -> Wt2 [1024][4096]
// blocks [12288,20480): LN1 row (id-12288): x f32 -> xn bf16
__global__ __launch_bounds__(256)
void prep_kernel(const float* __restrict__ x,
                 const float* __restrict__ Wq, const float* __restrict__ Wk,
                 const float* __restrict__ Wv, const float* __restrict__ Wo,
                 const float* __restrict__ W1, const float* __restrict__ W2,
                 u16* __restrict__ WtQKVO, u16* __restrict__ Wt1, u16* __restrict__ Wt2,
                 const float* __restrict__ gamma1, const float* __restrict__ beta1,
                 u16* __restrict__ xn) {
  const int id = blockIdx.x;
  const int tid = threadIdx.x;
  __shared__ float t[32][33];
  __shared__ float ps[4], pq[4];

  if (id < 12288) {
    // ---- transpose path ----
    const float* W;
    u16* Wt;
    int bx, by, K, N;
    if (id < 4096) {
      const int z = id >> 10, tile = id & 1023;
      W = (z == 0) ? Wq : (z == 1) ? Wk : (z == 2) ? Wv : Wo;
      Wt = WtQKVO + ((size_t)z << 20);
      bx = tile & 31; by = tile >> 5; K = D_MODEL; N = D_MODEL;
    } else if (id < 8192) {
      const int tl = id - 4096;
      W = W1; Wt = Wt1; bx = tl & 127; by = tl >> 7; K = D_MODEL; N = HIDDEN;
    } else {
      const int tl = id - 8192;
      W = W2; Wt = Wt2; bx = tl & 31; by = tl >> 5; K = HIDDEN; N = D_MODEL;
    }
    const int k0 = by * 32, n0 = bx * 32;
    const int tx = tid & 31, ty = tid >> 5;  // 32 x 8
#pragma unroll
    for (int p = 0; p < 4; ++p)
      t[ty + p * 8][tx] = W[(size_t)(k0 + ty + p * 8) * N + n0 + tx];
    __syncthreads();
#pragma unroll
    for (int p = 0; p < 4; ++p) {
      const int n = ty + p * 8;
      Wt[(size_t)(n0 + n) * K + k0 + tx] = f2bf(t[tx][n]);
    }
    return;
  }

  // ---- LN1 path ----
  const int row = id - 12288;
  const float4 v = ((const float4*)(x + (size_t)row * D_MODEL))[tid];
  float s = v.x + v.y + v.z + v.w;
  float q = v.x * v.x + v.y * v.y + v.z * v.z + v.w * v.w;
#pragma unroll
  for (int o = 32; o > 0; o >>= 1) { s += __shfl_down(s, o); q += __shfl_down(q, o); }
  const int wid = tid >> 6, lane = tid & 63;
  if (lane == 0) { ps[wid] = s; pq[wid] = q; }
  __syncthreads();
  s = ps[0] + ps[1] + ps[2] + ps[3];
  q = pq[0] + pq[1] + pq[2] + pq[3];
  const float mean = s * (1.0f / D_MODEL);
  const float var = q * (1.0f / D_MODEL) - mean * mean;
  const float rstd = rsqrtf(var + 1e-10f);
  const float4 gv = ((const float4*)gamma1)[tid];
  const float4 bv = ((const float4*)beta1)[tid];
  ushort4 o4;
  o4.x = f2bf((v.x - mean) * rstd * gv.x + bv.x);
  o4.y = f2bf((v.y - mean) * rstd * gv.y + bv.y);
  o4.z = f2bf((v.z - mean) * rstd * gv.z + bv.z);
  o4.w = f2bf((v.w - mean) * rstd * gv.w + bv.w);
  ((ushort4*)(xn + (size_t)row * D_MODEL))[tid] = o4;
}

// ---------------- LayerNorm (bf16 in): x1b bf16 [NTOK][D] -> xn bf16 ----------------
__global__ __launch_bounds__(256)
void ln_kernel_b(const u16* __restrict__ x, const float* __restrict__ gamma,
                 const float* __restrict__ beta, u16* __restrict__ out) {
  const int row = blockIdx.x;
  const int tid = threadIdx.x;
  const ushort4 uv = ((const ushort4*)(x + (size_t)row * D_MODEL))[tid];
  const float v0 = bf2f(uv.x), v1 = bf2f(uv.y), v2 = bf2f(uv.z), v3 = bf2f(uv.w);
  float s = v0 + v1 + v2 + v3;
  float q = v0 * v0 + v1 * v1 + v2 * v2 + v3 * v3;
#pragma unroll
  for (int o = 32; o > 0; o >>= 1) { s += __shfl_down(s, o); q += __shfl_down(q, o); }
  __shared__ float ps[4], pq[4];
  const int wid = tid >> 6, lane = tid & 63;
  if (lane == 0) { ps[wid] = s; pq[wid] = q; }
  __syncthreads();
  s = ps[0] + ps[1] + ps[2] + ps[3];
  q = pq[0] + pq[1] + pq[2] + pq[3];
  const float mean = s * (1.0f / D_MODEL);
  const float var = q * (1.0f / D_MODEL) - mean * mean;
  const float rstd = rsqrtf(var + 1e-10f);
  const float4 gv = ((const float4*)gamma)[tid];
  const float4 bv = ((const float4*)beta)[tid];
  ushort4 o4;
  o4.x = f2bf((v0 - mean) * rstd * gv.x + bv.x);
  o4.y = f2bf((v1 - mean) * rstd * gv.y + bv.y);
  o4.z = f2bf((v2 - mean) * rstd * gv.z + bv.z);
  o4.w = f2bf((v3 - mean) * rstd * gv.w + bv.w);
  ((ushort4*)(out + (size_t)row * D_MODEL))[tid] = o4;
}

// ---------------- gemm64: m97 structure, 128x128 tile, BK=64, 4 blocks/CU ----------------
// 256 threads = 4 waves (2m x 2n), per-wave 64x64 (4x4 frags), 32 MFMA / iter.
// Single 32 KB LDS buffer, __syncthreads (compiler vmcnt drain), 8 gload16/thread.
// 8-chunk XOR swizzle (c ^ row&7): fragment ds_read_b128 fully conflict-free.
// EPI 0: bf16 out, col bias.     EPI 1: f32 out += f32 res, col bias.
// EPI 2: gelu(erf)->bf16.  EPI 3: bf16, ROW bias, kv-permuted cols (V^T).
// EPI 6: fused QK dual output.  EPI 7: bf16 out = acc + bias + f32 res.
// EPI 8: f32 out = acc + bias + bf16 res.
template <int EPI, int KPY, int KPX>
__global__ __launch_bounds__(256, 4)
void gemm64(const u16* __restrict__ A, const u16* __restrict__ Bt,
            const float* __restrict__ bias, const float* __restrict__ bias2,
            const float* __restrict__ res, void* __restrict__ outp, void* __restrict__ outp2,
            int M, int N, int K) {
  __shared__ u16 As[128 * 64];
  __shared__ u16 Bs[128 * 64];
  const int tid = threadIdx.x;
  const int wid = tid >> 6, lane = tid & 63;
  const int g = lane >> 4, lr = lane & 15;
  const int wm = (wid & 1) << 6, wn = (wid >> 1) << 6;

  const int xcd = blockIdx.x & 7, l = blockIdx.x >> 3;
  int bx, by;
  if (KPY > 0) { by = xcd * KPY + (l % KPY); bx = l / KPY; }
  else         { bx = xcd * KPX + (l % KPX); by = l / KPX; }
  const int m0 = by * 128, n0 = bx * 128;

  const int NT = K >> 6;

  const int r0 = tid >> 3;
  const int csw = ((tid & 7) ^ (r0 & 7)) << 3;  // pre-swizzled u16 offset within row
  const u16* pA[4];
  const u16* pB[4];
#pragma unroll
  for (int i = 0; i < 4; ++i) {
    pA[i] = A + (size_t)(m0 + r0 + i * 32) * K + csw;
    pB[i] = Bt + (size_t)(n0 + r0 + i * 32) * K + csw;
  }
  const int db = (tid & 192) * 16;  // wave-uniform dest base (bytes)

  f32x4 acc[4][4] = {};

  for (int t = 0; t < NT; ++t) {
    __syncthreads();
#pragma unroll
    for (int i = 0; i < 4; ++i) {
      gload16(pA[i], (char*)As + db + i * 4096);
      gload16(pB[i], (char*)Bs + db + i * 4096);
      pA[i] += 64; pB[i] += 64;
    }
    __syncthreads();

#pragma unroll
    for (int ks = 0; ks < 2; ++ks) {
      bf16x8 af[4], bfr[4];
#pragma unroll
      for (int f = 0; f < 4; ++f) {
        const int ra = wm + f * 16 + lr;
        const int rb = wn + f * 16 + lr;
        const int co = ((ks * 4 + g) ^ (lr & 7)) * 8;
        af[f] = *(const bf16x8*)(As + ra * 64 + co);
        bfr[f] = *(const bf16x8*)(Bs + rb * 64 + co);
      }
      __builtin_amdgcn_s_setprio(1);
#pragma unroll
      for (int mf = 0; mf < 4; ++mf)
#pragma unroll
        for (int nf = 0; nf < 4; ++nf)
          acc[mf][nf] =
              __builtin_amdgcn_mfma_f32_16x16x32_bf16(af[mf], bfr[nf], acc[mf][nf], 0, 0, 0);
      __builtin_amdgcn_s_setprio(0);
    }
  }

  // ---- epilogue ----
#pragma unroll
  for (int mf = 0; mf < 4; ++mf)
#pragma unroll
    for (int nf = 0; nf < 4; ++nf) {
      const int gn = n0 + wn + nf * 16 + lr;
      const int gm = m0 + wm + mf * 16 + 4 * g;
#pragma unroll
      for (int r = 0; r < 4; ++r) {
        const float av = acc[mf][nf][r];
        if (EPI == 0) {
          ((u16*)outp)[(size_t)(gm + r) * N + gn] = f2bf(av + bias[gn]);
        } else if (EPI == 1) {
          const size_t idx = (size_t)(gm + r) * N + gn;
          ((float*)outp)[idx] = av + bias[gn] + res[idx];
        } else if (EPI == 2) {
          const float v = av + bias[gn];
          ((u16*)outp)[(size_t)(gm + r) * N + gn] =
              f2bf(0.5f * v * (1.0f + erff(v * 0.7071067811865475f)));
        } else if (EPI == 3) {
          const int gn_p = (gn & ~63) | ((gn & 15) << 2) | ((gn >> 4) & 3);
          ((u16*)outp)[(size_t)(gm + r) * N + gn_p] = f2bf(av + bias[gm + r]);
        } else if (EPI == 6) {
          const int side = gn >> 10, col = gn & 1023;
          u16* o = (u16*)(side ? outp2 : outp);
          float t_ = av + (side ? bias2[col] : bias[col]);
          if (!side) t_ *= 0.18033688011112042f;
          o[(size_t)(gm + r) * 1024 + col] = f2bf(t_);
        } else if (EPI == 7) {
          const size_t idx = (size_t)(gm + r) * N + gn;
          ((u16*)outp)[idx] = f2bf(av + bias[gn] + res[idx]);
        } else {  // EPI 8: f32 out = acc + bias + bf16 residual
          const size_t idx = (size_t)(gm + r) * N + gn;
          ((float*)outp)[idx] = av + bias[gn] + bf2f(((const u16*)res)[idx]);
        }
      }
    }
}

// ---------------- flash attention v5 (round-11/13/17/19 proven, 91.7 us) ----------------
// Q bf16 (pre-scaled by 0.125*log2e); K bf16; Vt bf16 [D][NTOK] kv-permuted; ctx bf16.
// No-max softmax in base 2.  Stride 76 (2-way banks).  XCD-affine bh mapping.
__global__ __launch_bounds__(256, 4)
void attn_kernel(const u16* __restrict__ Q, const u16* __restrict__ K,
                 const u16* __restrict__ Vt, u16* __restrict__ ctxo) {
  const int L = blockIdx.x;
  const int q0 = ((L >> 3) & 15) * 128;
  const int bh = ((L >> 7) << 3) | (L & 7);
  const int b = bh >> 4, h = bh & 15;
  const int tid = threadIdx.x, wid = tid >> 6, lane = tid & 63;
  const int g = lane >> 4, lr = lane & 15;
  const size_t base = ((size_t)b * SEQ) * D_MODEL + h * HDIM;
  const size_t vbase = ((size_t)h * HDIM) * NTOK + (size_t)b * SEQ;

#define AST 76
  __shared__ u16 Ks[64 * AST];
  __shared__ u16 Vts[64 * AST];
  __shared__ u16 Ps[128 * AST];

  const int qw = wid * 32;

#pragma unroll
  for (int i = 0; i < 4; ++i) {
    const int ch = tid + 256 * i, row = ch >> 3, j = ch & 7;
    *(bf16x8*)(Ps + row * AST + j * 8) =
        *(const bf16x8*)(Q + base + (size_t)(q0 + row) * D_MODEL + j * 8);
  }
  __syncthreads();
  bf16x8 aq[2][2];
#pragma unroll
  for (int qf = 0; qf < 2; ++qf)
#pragma unroll
    for (int ks = 0; ks < 2; ++ks)
      aq[qf][ks] = *(const bf16x8*)(Ps + (qw + qf * 16 + lr) * AST + ks * 32 + g * 8);

  f32x4 o[2][4] = {};
  float lrun[2][4] = {};

  for (int kv0 = 0; kv0 < SEQ; kv0 += 64) {
    __syncthreads();
#pragma unroll
    for (int i = 0; i < 2; ++i) {
      const int row = (tid >> 3) + i * 32, j = tid & 7;
      *(bf16x8*)(Ks + row * AST + j * 8) =
          *(const bf16x8*)(K + base + (size_t)(kv0 + row) * D_MODEL + j * 8);
      *(bf16x8*)(Vts + row * AST + j * 8) =
          *(const bf16x8*)(Vt + vbase + (size_t)row * NTOK + kv0 + j * 8);
    }
    __syncthreads();

    f32x4 s[2][4] = {};
    __builtin_amdgcn_s_setprio(1);
#pragma unroll
    for (int ks = 0; ks < 2; ++ks)
#pragma unroll
      for (int kf = 0; kf < 4; ++kf) {
        const bf16x8 bk = *(const bf16x8*)(Ks + (kf * 16 + lr) * AST + ks * 32 + g * 8);
#pragma unroll
        for (int qf = 0; qf < 2; ++qf)
          s[qf][kf] = __builtin_amdgcn_mfma_f32_16x16x32_bf16(aq[qf][ks], bk, s[qf][kf], 0, 0, 0);
      }
    __builtin_amdgcn_s_setprio(0);

#pragma unroll
    for (int qf = 0; qf < 2; ++qf)
#pragma unroll
      for (int r = 0; r < 4; ++r) {
        float p0, p1, p2, p3;
        asm("v_exp_f32 %0, %1" : "=v"(p0) : "v"(s[qf][0][r]));
        asm("v_exp_f32 %0, %1" : "=v"(p1) : "v"(s[qf][1][r]));
        asm("v_exp_f32 %0, %1" : "=v"(p2) : "v"(s[qf][2][r]));
        asm("v_exp_f32 %0, %1" : "=v"(p3) : "v"(s[qf][3][r]));
        lrun[qf][r] += (p0 + p1) + (p2 + p3);
        unsigned lo, hi;
        asm("v_cvt_pk_bf16_f32 %0, %1, %2" : "=v"(lo) : "v"(p0), "v"(p1));
        asm("v_cvt_pk_bf16_f32 %0, %1, %2" : "=v"(hi) : "v"(p2), "v"(p3));
        *(uint2*)(Ps + (qw + qf * 16 + 4 * g + r) * AST + lr * 4) = make_uint2(lo, hi);
      }
    asm volatile("s_waitcnt lgkmcnt(0)" ::: "memory");

    __builtin_amdgcn_s_setprio(1);
#pragma unroll
    for (int ks = 0; ks < 2; ++ks) {
      bf16x8 pf[2];
#pragma unroll
      for (int qf = 0; qf < 2; ++qf)
        pf[qf] = *(const bf16x8*)(Ps + (qw + qf * 16 + lr) * AST + ks * 32 + g * 8);
#pragma unroll
      for (int df = 0; df < 4; ++df) {
        const bf16x8 vf = *(const bf16x8*)(Vts + (df * 16 + lr) * AST + ks * 32 + g * 8);
#pragma unroll
        for (int qf = 0; qf < 2; ++qf)
          o[qf][df] = __builtin_amdgcn_mfma_f32_16x16x32_bf16(pf[qf], vf, o[qf][df], 0, 0, 0);
      }
    }
    __builtin_amdgcn_s_setprio(0);
  }

#pragma unroll
  for (int off = 1; off < 16; off <<= 1)
#pragma unroll
    for (int qf = 0; qf < 2; ++qf)
#pragma unroll
      for (int r = 0; r < 4; ++r)
        lrun[qf][r] += __shfl_xor(lrun[qf][r], off);

#pragma unroll
  for (int qf = 0; qf < 2; ++qf)
#pragma unroll
    for (int r = 0; r < 4; ++r) {
      const float rinv = 1.0f / lrun[qf][r];
      const int qrow = q0 + qw + qf * 16 + 4 * g + r;
#pragma unroll
      for (int df = 0; df < 4; ++df)
        ctxo[base + (size_t)qrow * D_MODEL + df * 16 + lr] = f2bf(o[qf][df][r] * rinv);
    }
#undef AST
}

extern "C" void kernel_launch(void* const* d_in, const int* in_sizes, int n_in,
                              void* d_out, int out_size, void* d_ws, size_t ws_size,
                              hipStream_t stream) {
  const float* x  = (const float*)d_in[0];
  const float* Wq = (const float*)d_in[1];
  const float* bq = (const float*)d_in[2];
  const float* Wk = (const float*)d_in[3];
  const float* bk = (const float*)d_in[4];
  const float* Wv = (const float*)d_in[5];
  const float* bv = (const float*)d_in[6];
  const float* Wo = (const float*)d_in[7];
  const float* bo = (const float*)d_in[8];
  const float* W1 = (const float*)d_in[9];
  const float* b1 = (const float*)d_in[10];
  const float* W2 = (const float*)d_in[11];
  const float* b2 = (const float*)d_in[12];
  const float* gamma1 = (const float*)d_in[13];
  const float* beta1  = (const float*)d_in[14];
  const float* gamma2 = (const float*)d_in[15];
  const float* beta2  = (const float*)d_in[16];
  float* out = (float*)d_out;

  const size_t M1 = 1u << 20;  // 1M elems
  u16* w   = (u16*)d_ws;
  u16* WtQ = w;                // [1024][1024]; WtK adjacent -> fused Bt [2048][1024]
  u16* WtV = w + 2 * M1;
  u16* WtO = w + 3 * M1;
  u16* Wt1 = w + 4 * M1;   // [4096][1024]
  u16* Wt2 = w + 8 * M1;   // [1024][4096]
  u16* xn  = w + 12 * M1;
  u16* Qb  = w + 20 * M1;
  u16* Kb  = w + 28 * M1;
  u16* Vtb = w + 36 * M1;  // V^T [1024][8192], kv-permuted within 64-blocks
  u16* ctx = w + 44 * M1;
  u16* hb  = w + 20 * M1;  // h [8192][4096] aliases Q/K/Vt/ctx (dead by FFN1)
  u16* x1b = w + 52 * M1;  // x1 residual in bf16 [8192][1024]

  // fused prologue: all 6 transposes + LN1 in one launch
  prep_kernel<<<20480, 256, 0, stream>>>(x, Wq, Wk, Wv, Wo, W1, W2,
                                         WtQ, Wt1, Wt2, gamma1, beta1, xn);

  // fused Q+K projection: Bt = [WtQ;WtK], N=2048 -> 1024 blocks
  gemm64<6, 8, 0><<<1024, 256, 0, stream>>>(xn, WtQ, bq, bk, nullptr, Qb, Kb,
                                            NTOK, 2048, D_MODEL);
  // V^T: C[d][s] = WtV[d][:] . xn[s][:]  (row bias bv[d]), kv-permuted columns
  gemm64<3, 0, 8><<<512, 256, 0, stream>>>(WtV, xn, bv, nullptr, nullptr, Vtb, nullptr,
                                           D_MODEL, NTOK, D_MODEL);

  attn_kernel<<<1024, 256, 0, stream>>>(Qb, Kb, Vtb, ctx);

  // Wo + residual(x f32) -> x1b (bf16)
  gemm64<7, 8, 0><<<512, 256, 0, stream>>>(ctx, WtO, bo, nullptr, x, x1b, nullptr,
                                           NTOK, D_MODEL, D_MODEL);

  ln_kernel_b<<<NTOK, 256, 0, stream>>>(x1b, gamma2, beta2, xn);

  // FFN1: gemm64, full chip
  gemm64<2, 8, 0><<<2048, 256, 0, stream>>>(xn, Wt1, b1, nullptr, nullptr, hb, nullptr,
                                            NTOK, HIDDEN, D_MODEL);
  // FFN2 + residual(x1b bf16) -> out (f32)
  gemm64<8, 8, 0><<<512, 256, 0, stream>>>(hb, Wt2, b2, nullptr, (const float*)x1b, out,
                                           nullptr, NTOK, D_MODEL, HIDDEN);
}